// Round 2
// baseline (216.223 us; speedup 1.0000x reference)
//
#include <hip/hip_runtime.h>
#include <hip/hip_bf16.h>
#include <math.h>

__device__ __forceinline__ float leaky(float x) { return x > 0.0f ? x : 0.01f * x; }

// ---------- stage 1: both HW-mean reductions in one kernel ----------
// blocks [0,16384): x_mid [128,512,28,28] -> xm_mean [128,512]  (1 wave / row of 784)
// blocks [16384,32768): x_deep [128,2048,7,7] -> xd_mean [128,2048] (16 lanes / row of 49)
__global__ __launch_bounds__(256) void means_kernel(const float* __restrict__ xm,
                                                    const float* __restrict__ xd,
                                                    float* __restrict__ xm_mean,
                                                    float* __restrict__ xd_mean)
{
    int blk = blockIdx.x;
    int tid = threadIdx.x;
    if (blk < 16384) {
        int lane = tid & 63;
        int wid  = tid >> 6;
        int row  = blk * 4 + wid;                  // 0..65535
        const float4* r = (const float4*)(xm + (size_t)row * 784);
        float s = 0.0f;
        for (int i = lane; i < 196; i += 64) {
            float4 v = r[i];
            s += v.x + v.y + v.z + v.w;
        }
        #pragma unroll
        for (int off = 32; off; off >>= 1) s += __shfl_xor(s, off);
        if (lane == 0) xm_mean[row] = s * (1.0f / 784.0f);
    } else {
        int b2  = blk - 16384;
        int sub = tid & 15;
        int r   = tid >> 4;
        int row = b2 * 16 + r;                     // 0..262143
        const float* base = xd + (size_t)row * 49;
        float s = base[sub] + base[sub + 16] + base[sub + 32];
        if (sub == 0) s += base[48];
        #pragma unroll
        for (int off = 8; off; off >>= 1) s += __shfl_xor(s, off);
        if (sub == 0) xd_mean[row] = s * (1.0f / 49.0f);
    }
}

// ---------- split-K GEMM with FUSED split-K input reduce + activation ----------
// C = act(sum_p A_p)[128,K] * B[N,K]^T ; partials out to P[z][s][128*N]
// A partial slices are contiguous with stride 128*K. BM=128 BN=32 BK=32.
__global__ __launch_bounds__(256) void gemm_fused(
    const float* __restrict__ A0, int A0S, int A0act,
    const float* __restrict__ A1, int A1S, int A1act,
    const float* __restrict__ B0, const float* __restrict__ B1,
    float* __restrict__ P, int N, int K, int S)
{
    __shared__ float As[128][34];
    __shared__ float Bs[32][34];

    const int z   = blockIdx.z;
    const float* A = z ? A1 : A0;
    const float* B = z ? B1 : B0;
    const int AS  = z ? A1S : A0S;
    const int act = z ? A1act : A0act;
    const size_t Astride = (size_t)128 * K;

    const int n0 = blockIdx.x * 32;
    const int s  = blockIdx.y;
    const int Kc = K / S;
    const int k0 = s * Kc;
    float* Pb = P + ((size_t)(z * S + s)) * 128 * N;

    const int tid = threadIdx.x;
    const int tx = tid & 7;
    const int ty = tid >> 3;

    float acc[4][4] = {};

    for (int kt = k0; kt < k0 + Kc; kt += 32) {
        // stage A 128x32 with partial-sum + optional leaky
        #pragma unroll
        for (int it = 0; it < 4; ++it) {
            int idx = it * 256 + tid;
            int m = idx >> 3, kq = idx & 7;
            size_t off = (size_t)m * K + kt + kq * 4;
            float4 v = *(const float4*)(A + off);
            for (int p = 1; p < AS; ++p) {
                float4 u = *(const float4*)(A + (size_t)p * Astride + off);
                v.x += u.x; v.y += u.y; v.z += u.z; v.w += u.w;
            }
            if (act) { v.x = leaky(v.x); v.y = leaky(v.y); v.z = leaky(v.z); v.w = leaky(v.w); }
            As[m][kq * 4 + 0] = v.x; As[m][kq * 4 + 1] = v.y;
            As[m][kq * 4 + 2] = v.z; As[m][kq * 4 + 3] = v.w;
        }
        // stage B 32x32
        {
            int m = tid >> 3, kq = tid & 7;
            float4 v = *(const float4*)(B + (size_t)(n0 + m) * K + kt + kq * 4);
            Bs[m][kq * 4 + 0] = v.x; Bs[m][kq * 4 + 1] = v.y;
            Bs[m][kq * 4 + 2] = v.z; Bs[m][kq * 4 + 3] = v.w;
        }
        __syncthreads();

        #pragma unroll
        for (int kk = 0; kk < 32; kk += 2) {
            float2 a[4], b[4];
            #pragma unroll
            for (int i = 0; i < 4; ++i) a[i] = *(const float2*)&As[ty * 4 + i][kk];
            #pragma unroll
            for (int j = 0; j < 4; ++j) b[j] = *(const float2*)&Bs[tx * 4 + j][kk];
            #pragma unroll
            for (int i = 0; i < 4; ++i)
                #pragma unroll
                for (int j = 0; j < 4; ++j)
                    acc[i][j] += a[i].x * b[j].x + a[i].y * b[j].y;
        }
        __syncthreads();
    }

    #pragma unroll
    for (int i = 0; i < 4; ++i) {
        float4 v = { acc[i][0], acc[i][1], acc[i][2], acc[i][3] };
        *(float4*)(Pb + (size_t)(ty * 4 + i) * N + n0 + tx * 4) = v;
    }
}

// ---------- tail: P_E reduce + layer-3 matvecs + texture/sim/class/q (1 block / sample) ----------
__global__ __launch_bounds__(64) void tail_kernel(
    const float* __restrict__ PE,                 // [2][8][128*512] partials of layer 2
    const float* __restrict__ ow3, const float* __restrict__ sw3,
    const float* __restrict__ tw1, const float* __restrict__ tw2,
    const float* __restrict__ cw1, const float* __restrict__ cw2,
    const float* __restrict__ qw1, const float* __restrict__ qw2,
    const float* __restrict__ center, const float* __restrict__ proto,
    float* __restrict__ ce_t, float* __restrict__ osv,
    float* __restrict__ csv, float* __restrict__ alv)
{
    const int b = blockIdx.x;
    const int o = threadIdx.x;                    // one wave
    __shared__ float o2r[512], s2r[512];
    __shared__ float t1[64], c1[64], q1[64], o3s[64], s3s[64];

    // reduce layer-2 partials (8 slices, 2 paths) + leaky
    for (int e = o; e < 512; e += 64) {
        float a0 = 0.0f, a1 = 0.0f;
        #pragma unroll
        for (int p = 0; p < 8; ++p) {
            a0 += PE[(size_t)p       * 65536 + b * 512 + e];
            a1 += PE[(size_t)(8 + p) * 65536 + b * 512 + e];
        }
        o2r[e] = leaky(a0);
        s2r[e] = leaky(a1);
    }
    __syncthreads();

    // layer 3 matvecs: origin[o], shallow[o]
    float ao = 0.0f, as_ = 0.0f;
    for (int j = 0; j < 512; ++j) {
        ao  += ow3[o * 512 + j] * o2r[j];
        as_ += sw3[o * 512 + j] * s2r[j];
    }
    float org = leaky(ao);
    float sh  = leaky(as_);
    o3s[o] = org; s3s[o] = sh;
    __syncthreads();

    // texture layer 1: in = [shallow, shallow - center]
    float acc = 0.0f;
    for (int j = 0; j < 64; ++j) acc += tw1[o * 128 + j] * s3s[j];
    for (int j = 0; j < 64; ++j) acc += tw1[o * 128 + 64 + j] * (s3s[j] - center[j]);
    t1[o] = leaky(acc);
    __syncthreads();
    acc = 0.0f;
    for (int j = 0; j < 64; ++j) acc += tw2[o * 64 + j] * t1[j];
    float tex = leaky(acc);

    // sim[k] = ||texture - proto_k||^2
    float sim[4];
    #pragma unroll
    for (int k = 0; k < 4; ++k) {
        float d = tex - proto[k * 64 + o];
        float v = d * d;
        #pragma unroll
        for (int off = 32; off; off >>= 1) v += __shfl_xor(v, off);
        sim[k] = v;
    }
    int cat = 0; float best = sim[0];
    #pragma unroll
    for (int k = 1; k < 4; ++k) if (sim[k] > best) { best = sim[k]; cat = k; }
    float sume = 0.0f;
    #pragma unroll
    for (int k = 0; k < 4; ++k) sume += expf(sim[k] - best);

    // class path: in = [origin, origin - proto[cat]]
    acc = 0.0f;
    for (int j = 0; j < 64; ++j) acc += cw1[o * 128 + j] * o3s[j];
    for (int j = 0; j < 64; ++j) acc += cw1[o * 128 + 64 + j] * (o3s[j] - proto[cat * 64 + j]);
    c1[o] = leaky(acc);
    __syncthreads();
    acc = 0.0f;
    for (int j = 0; j < 64; ++j) acc += cw2[o * 64 + j] * c1[j];
    float cf = leaky(acc);
    float dc = cf - center[o];
    float cs = dc * dc;
    #pragma unroll
    for (int off = 32; off; off >>= 1) cs += __shfl_xor(cs, off);

    // q path
    acc = 0.0f;
    for (int j = 0; j < 64; ++j) acc += qw1[o * 64 + j] * o3s[j];
    q1[o] = leaky(acc);
    __syncthreads();
    acc = 0.0f;
    for (int j = 0; j < 64; ++j) acc += qw2[o * 64 + j] * q1[j];
    float qf = leaky(acc);
    float dq = qf - center[o];
    float os = dq * dq;
    #pragma unroll
    for (int off = 32; off; off >>= 1) os += __shfl_xor(os, off);

    if (o == 0) {
        ce_t[b] = logf(sume);
        osv[b]  = os;
        csv[b]  = cs;
        alv[b]  = fabsf(os - cs);
    }
}

// ---------- finalize ----------
__global__ __launch_bounds__(128) void finalize_kernel(
    const float* __restrict__ ce_t, const float* __restrict__ osv,
    const float* __restrict__ csv, const float* __restrict__ alv,
    float* __restrict__ out)
{
    int t = threadIdx.x;
    float v[4] = { ce_t[t], osv[t], csv[t], alv[t] };
    __shared__ float tmp[4][2];
    int lane = t & 63, w = t >> 6;
    #pragma unroll
    for (int i = 0; i < 4; ++i) {
        float x = v[i];
        #pragma unroll
        for (int off = 32; off; off >>= 1) x += __shfl_xor(x, off);
        if (lane == 0) tmp[i][w] = x;
    }
    __syncthreads();
    if (t < 4) out[t] = (tmp[t][0] + tmp[t][1]) * (1.0f / 128.0f);
}

// ---------- launcher ----------
extern "C" void kernel_launch(void* const* d_in, const int* in_sizes, int n_in,
                              void* d_out, int out_size, void* d_ws, size_t ws_size,
                              hipStream_t stream)
{
    const float* x_mid     = (const float*)d_in[0];
    const float* x_deep    = (const float*)d_in[1];
    const float* w_shallow = (const float*)d_in[2];
    const float* ow1 = (const float*)d_in[3];
    const float* ow2 = (const float*)d_in[4];
    const float* ow3 = (const float*)d_in[5];
    const float* sw1 = (const float*)d_in[6];
    const float* sw2 = (const float*)d_in[7];
    const float* sw3 = (const float*)d_in[8];
    const float* tw1 = (const float*)d_in[9];
    const float* tw2 = (const float*)d_in[10];
    const float* cw1 = (const float*)d_in[11];
    const float* cw2 = (const float*)d_in[12];
    const float* qw1 = (const float*)d_in[13];
    const float* qw2 = (const float*)d_in[14];
    const float* center = (const float*)d_in[15];
    const float* proto  = (const float*)d_in[16];
    float* out = (float*)d_out;

    float* w = (float*)d_ws;
    float* xm_mean = w;                        // 65536
    float* xd_mean = w + 65536;                // 262144
    float* P_C = w + 327680;                   // 4 * 262144 = 1048576
    float* P_D = w + 1376256;                  // 2*4*131072 = 1048576
    float* P_E = w + 2424832;                  // 2*8*65536  = 1048576
    float* ce_t = w + 3473408;                 // 128
    float* osv  = w + 3473536;
    float* csv  = w + 3473664;
    float* alv  = w + 3473792;

    // stage 1: both means
    means_kernel<<<32768, 256, 0, stream>>>(x_mid, x_deep, xm_mean, xd_mean);

    // stage 2 (C): shallow_in partials = xm_mean @ w_shallow^T  [128,2048], S=4
    gemm_fused<<<dim3(64, 4, 1), 256, 0, stream>>>(
        xm_mean, 1, 0, nullptr, 1, 0, w_shallow, nullptr, P_C, 2048, 512, 4);

    // stage 3 (D): layer 1, A0 = xd_mean direct, A1 = reduce(P_C) no act. S=4
    gemm_fused<<<dim3(32, 4, 2), 256, 0, stream>>>(
        xd_mean, 1, 0, P_C, 4, 0, ow1, sw1, P_D, 1024, 2048, 4);

    // stage 4 (E): layer 2, A = leaky(reduce(P_D)) per path. S=8
    gemm_fused<<<dim3(16, 8, 2), 256, 0, stream>>>(
        P_D, 4, 1, P_D + (size_t)4 * 131072, 4, 1, ow2, sw2, P_E, 512, 1024, 8);

    // stage 5: tail (includes P_E reduce + layer-3 matvecs)
    tail_kernel<<<128, 64, 0, stream>>>(P_E, ow3, sw3, tw1, tw2, cw1, cw2, qw1, qw2,
                                        center, proto, ce_t, osv, csv, alv);

    // stage 6: finalize
    finalize_kernel<<<1, 128, 0, stream>>>(ce_t, osv, csv, alv, out);
}

// Round 3
// 112.204 us; speedup vs baseline: 1.9270x; 1.9270x over previous
//
#include <hip/hip_runtime.h>
#include <hip/hip_bf16.h>
#include <math.h>

typedef __attribute__((ext_vector_type(8))) short bf16x8;
typedef __attribute__((ext_vector_type(4))) float f32x4;

__device__ __forceinline__ float leaky(float x) { return x > 0.0f ? x : 0.01f * x; }

// fp32 -> bf16 round-to-nearest-even
__device__ __forceinline__ unsigned short f2b(float f) {
    unsigned u = __builtin_bit_cast(unsigned, f);
    u += 0x7fffu + ((u >> 16) & 1u);
    return (unsigned short)(u >> 16);
}
__device__ __forceinline__ float b2f(unsigned short h) {
    unsigned u = ((unsigned)h) << 16;
    return __builtin_bit_cast(float, u);
}

// ---------- stage 1: both HW means -> bf16 ----------
__global__ __launch_bounds__(256) void means_kernel(const float* __restrict__ xm,
                                                    const float* __restrict__ xd,
                                                    unsigned short* __restrict__ xm_b,
                                                    unsigned short* __restrict__ xd_b)
{
    int blk = blockIdx.x;
    int tid = threadIdx.x;
    if (blk < 16384) {
        int lane = tid & 63;
        int wid  = tid >> 6;
        int row  = blk * 4 + wid;                  // 0..65535
        const float4* r = (const float4*)(xm + (size_t)row * 784);
        float s = 0.0f;
        for (int i = lane; i < 196; i += 64) {
            float4 v = r[i];
            s += v.x + v.y + v.z + v.w;
        }
        #pragma unroll
        for (int off = 32; off; off >>= 1) s += __shfl_xor(s, off);
        if (lane == 0) xm_b[row] = f2b(s * (1.0f / 784.0f));
    } else {
        int b2  = blk - 16384;
        int sub = tid & 15;
        int r   = tid >> 4;
        int row = b2 * 16 + r;                     // 0..262143
        const float* base = xd + (size_t)row * 49;
        float s = base[sub] + base[sub + 16] + base[sub + 32];
        if (sub == 0) s += base[48];
        #pragma unroll
        for (int off = 8; off; off >>= 1) s += __shfl_xor(s, off);
        if (sub == 0) xd_b[row] = f2b(s * (1.0f / 49.0f));
    }
}

// ---------- MFMA split-K GEMM, direct-from-memory fragments (no LDS) ----------
// out[m][n] = sum_k A[m][k] * B[n][k]; A bf16 [128,K], B fp32 [N,K] (cvt in reg)
// grid (N/32, S, paths); block 512 = 8 waves; wave w: rows 16w..16w+15, cols n0..n0+31
__global__ __launch_bounds__(512) void gemm_mfma(
    const unsigned short* __restrict__ A0, const unsigned short* __restrict__ A1,
    const float* __restrict__ B0, const float* __restrict__ B1,
    float* __restrict__ P, int N, int K, int S)
{
    const int z = blockIdx.z;
    const unsigned short* A = z ? A1 : A0;
    const float*          B = z ? B1 : B0;
    const int n0 = blockIdx.x * 32;
    const int s  = blockIdx.y;
    const int Kc = K / S;
    const int k0 = s * Kc;

    const int tid = threadIdx.x;
    const int w  = tid >> 6;
    const int l  = tid & 63;
    const int lr = l & 15;        // row within fragment
    const int lc = l >> 4;        // k-chunk (0..3), 8 elems each
    const int m0 = w * 16;

    const unsigned short* Ap = A + (size_t)(m0 + lr) * K + k0 + lc * 8;
    const float* Bp0 = B + (size_t)(n0 +      lr) * K + k0 + lc * 8;
    const float* Bp1 = B + (size_t)(n0 + 16 + lr) * K + k0 + lc * 8;

    f32x4 acc0 = {0.f, 0.f, 0.f, 0.f};
    f32x4 acc1 = {0.f, 0.f, 0.f, 0.f};

    for (int kt = 0; kt < Kc; kt += 32) {
        bf16x8 a = *(const bf16x8*)(Ap + kt);
        float4 u0 = *(const float4*)(Bp0 + kt);
        float4 u1 = *(const float4*)(Bp0 + kt + 4);
        float4 v0 = *(const float4*)(Bp1 + kt);
        float4 v1 = *(const float4*)(Bp1 + kt + 4);
        bf16x8 b0, b1;
        b0[0] = (short)f2b(u0.x); b0[1] = (short)f2b(u0.y);
        b0[2] = (short)f2b(u0.z); b0[3] = (short)f2b(u0.w);
        b0[4] = (short)f2b(u1.x); b0[5] = (short)f2b(u1.y);
        b0[6] = (short)f2b(u1.z); b0[7] = (short)f2b(u1.w);
        b1[0] = (short)f2b(v0.x); b1[1] = (short)f2b(v0.y);
        b1[2] = (short)f2b(v0.z); b1[3] = (short)f2b(v0.w);
        b1[4] = (short)f2b(v1.x); b1[5] = (short)f2b(v1.y);
        b1[6] = (short)f2b(v1.z); b1[7] = (short)f2b(v1.w);
        acc0 = __builtin_amdgcn_mfma_f32_16x16x32_bf16(a, b0, acc0, 0, 0, 0);
        acc1 = __builtin_amdgcn_mfma_f32_16x16x32_bf16(a, b1, acc1, 0, 0, 0);
    }

    // C/D layout: col = lane&15, row = (lane>>4)*4 + reg
    float* Pb = P + ((size_t)(z * S + s)) * 128 * N;
    #pragma unroll
    for (int r = 0; r < 4; ++r) {
        int m = m0 + lc * 4 + r;
        Pb[(size_t)m * N + n0 + lr]      = acc0[r];
        Pb[(size_t)m * N + n0 + 16 + lr] = acc1[r];
    }
}

// ---------- split-K partial reduce -> bf16 activation ----------
__global__ void reduce_b(const float* __restrict__ P,
                         unsigned short* __restrict__ out0,
                         unsigned short* __restrict__ out1,
                         int MN, int S, int paths, int do_act)
{
    int idx = blockIdx.x * blockDim.x + threadIdx.x;
    if (idx >= paths * MN) return;
    int z = idx / MN, e = idx - z * MN;
    const float* base = P + (size_t)z * S * MN;
    float s = 0.0f;
    for (int p = 0; p < S; ++p) s += base[(size_t)p * MN + e];
    if (do_act) s = leaky(s);
    unsigned short* o = z ? out1 : out0;
    o[e] = f2b(s);
}

// ---------- tail: P_E reduce + layer-3 matvecs + texture/sim/class/q ----------
// one block (256 threads) per sample
__global__ __launch_bounds__(256) void tail_kernel(
    const float* __restrict__ PE,                  // [2][8][128*512] fp32 partials
    const float* __restrict__ ow3, const float* __restrict__ sw3,
    const float* __restrict__ tw1, const float* __restrict__ tw2,
    const float* __restrict__ cw1, const float* __restrict__ cw2,
    const float* __restrict__ qw1, const float* __restrict__ qw2,
    const float* __restrict__ center, const float* __restrict__ proto,
    float* __restrict__ ce_t, float* __restrict__ osv,
    float* __restrict__ csv, float* __restrict__ alv)
{
    const int b = blockIdx.x;
    const int t = threadIdx.x;
    __shared__ float o2r[512], s2r[512];
    __shared__ float red[2][64][4];
    __shared__ float o3s[64], s3s[64], t1[64], c1[64], q1[64];

    // reduce layer-2 partials (8 slices, 2 paths) + leaky
    for (int e = t; e < 512; e += 256) {
        float a0 = 0.0f, a1 = 0.0f;
        #pragma unroll
        for (int p = 0; p < 8; ++p) {
            a0 += PE[(size_t)p       * 65536 + b * 512 + e];
            a1 += PE[(size_t)(8 + p) * 65536 + b * 512 + e];
        }
        o2r[e] = leaky(a0);
        s2r[e] = leaky(a1);
    }
    __syncthreads();

    // layer-3 matvecs, 4-way K-split: thread t -> out o=t&63, quarter q=t>>6
    {
        int o = t & 63, q = t >> 6;
        float ao = 0.0f, as_ = 0.0f;
        const float* wro = ow3 + (size_t)o * 512 + q * 128;
        const float* wrs = sw3 + (size_t)o * 512 + q * 128;
        const float* xo = o2r + q * 128;
        const float* xs = s2r + q * 128;
        for (int j = 0; j < 128; ++j) {
            ao  += wro[j] * xo[j];
            as_ += wrs[j] * xs[j];
        }
        red[0][o][q] = ao;
        red[1][o][q] = as_;
    }
    __syncthreads();
    if (t < 64) {
        o3s[t] = leaky(red[0][t][0] + red[0][t][1] + red[0][t][2] + red[0][t][3]);
        s3s[t] = leaky(red[1][t][0] + red[1][t][1] + red[1][t][2] + red[1][t][3]);
    }
    __syncthreads();

    // ---- wave-0 per-sample tail (barriers at top level, all threads) ----
    int o = t;
    float acc;
    if (t < 64) {
        acc = 0.0f;
        for (int j = 0; j < 64; ++j) acc += tw1[o * 128 + j] * s3s[j];
        for (int j = 0; j < 64; ++j) acc += tw1[o * 128 + 64 + j] * (s3s[j] - center[j]);
        t1[o] = leaky(acc);
    }
    __syncthreads();

    float sim0 = 0, sim1 = 0, sim2 = 0, sim3 = 0;
    int cat = 0;
    float ce_val = 0;
    if (t < 64) {
        acc = 0.0f;
        for (int j = 0; j < 64; ++j) acc += tw2[o * 64 + j] * t1[j];
        float tex = leaky(acc);
        float sim[4];
        #pragma unroll
        for (int k = 0; k < 4; ++k) {
            float d = tex - proto[k * 64 + o];
            float v = d * d;
            #pragma unroll
            for (int off = 32; off; off >>= 1) v += __shfl_xor(v, off);
            sim[k] = v;
        }
        float best = sim[0];
        #pragma unroll
        for (int k = 1; k < 4; ++k) if (sim[k] > best) { best = sim[k]; cat = k; }
        float sume = 0.0f;
        #pragma unroll
        for (int k = 0; k < 4; ++k) sume += expf(sim[k] - best);
        ce_val = logf(sume);
        // class layer 1
        acc = 0.0f;
        for (int j = 0; j < 64; ++j) acc += cw1[o * 128 + j] * o3s[j];
        for (int j = 0; j < 64; ++j) acc += cw1[o * 128 + 64 + j] * (o3s[j] - proto[cat * 64 + j]);
        c1[o] = leaky(acc);
    }
    __syncthreads();
    if (t < 64) {
        acc = 0.0f;
        for (int j = 0; j < 64; ++j) acc += cw2[o * 64 + j] * c1[j];
        float cf = leaky(acc);
        float dc = cf - center[o];
        float cs = dc * dc;
        #pragma unroll
        for (int off = 32; off; off >>= 1) cs += __shfl_xor(cs, off);
        // q layer 1
        acc = 0.0f;
        for (int j = 0; j < 64; ++j) acc += qw1[o * 64 + j] * o3s[j];
        q1[o] = leaky(acc);
        c1[o] = 0.0f;  // reuse below? no — keep cs in reg
        red[0][o][0] = cs;   // stash class svdd (same for all lanes after reduce)
    }
    __syncthreads();
    if (t < 64) {
        acc = 0.0f;
        for (int j = 0; j < 64; ++j) acc += qw2[o * 64 + j] * q1[j];
        float qf = leaky(acc);
        float dq = qf - center[o];
        float os = dq * dq;
        #pragma unroll
        for (int off = 32; off; off >>= 1) os += __shfl_xor(os, off);
        if (o == 0) {
            float cs = red[0][0][0];
            ce_t[b] = ce_val;
            osv[b]  = os;
            csv[b]  = cs;
            alv[b]  = fabsf(os - cs);
        }
    }
}

// ---------- finalize ----------
__global__ __launch_bounds__(128) void finalize_kernel(
    const float* __restrict__ ce_t, const float* __restrict__ osv,
    const float* __restrict__ csv, const float* __restrict__ alv,
    float* __restrict__ out)
{
    int t = threadIdx.x;
    float v[4] = { ce_t[t], osv[t], csv[t], alv[t] };
    __shared__ float tmp[4][2];
    int lane = t & 63, w = t >> 6;
    #pragma unroll
    for (int i = 0; i < 4; ++i) {
        float x = v[i];
        #pragma unroll
        for (int off = 32; off; off >>= 1) x += __shfl_xor(x, off);
        if (lane == 0) tmp[i][w] = x;
    }
    __syncthreads();
    if (t < 4) out[t] = (tmp[t][0] + tmp[t][1]) * (1.0f / 128.0f);
}

// ---------- launcher ----------
extern "C" void kernel_launch(void* const* d_in, const int* in_sizes, int n_in,
                              void* d_out, int out_size, void* d_ws, size_t ws_size,
                              hipStream_t stream)
{
    const float* x_mid     = (const float*)d_in[0];
    const float* x_deep    = (const float*)d_in[1];
    const float* w_shallow = (const float*)d_in[2];
    const float* ow1 = (const float*)d_in[3];
    const float* ow2 = (const float*)d_in[4];
    const float* ow3 = (const float*)d_in[5];
    const float* sw1 = (const float*)d_in[6];
    const float* sw2 = (const float*)d_in[7];
    const float* sw3 = (const float*)d_in[8];
    const float* tw1 = (const float*)d_in[9];
    const float* tw2 = (const float*)d_in[10];
    const float* cw1 = (const float*)d_in[11];
    const float* cw2 = (const float*)d_in[12];
    const float* qw1 = (const float*)d_in[13];
    const float* qw2 = (const float*)d_in[14];
    const float* center = (const float*)d_in[15];
    const float* proto  = (const float*)d_in[16];
    float* out = (float*)d_out;

    char* wb = (char*)d_ws;
    unsigned short* xm_b = (unsigned short*)(wb);              // 128K
    unsigned short* xd_b = (unsigned short*)(wb + (1<<20));    // 512K
    unsigned short* sh_b = (unsigned short*)(wb + (2<<20));    // 512K
    unsigned short* o1_b = (unsigned short*)(wb + (3<<20));    // 256K
    unsigned short* s1_b = (unsigned short*)(wb + (4<<20));    // 256K
    float* P_C  = (float*)(wb + (8<<20));                      // 4 MB
    float* P_D  = (float*)(wb + (16<<20));                     // 8 MB
    float* P_E  = (float*)(wb + (32<<20));                     // 4 MB
    float* ce_t = (float*)(wb + (48<<20));
    float* osv  = ce_t + 128;
    float* csv  = ce_t + 256;
    float* alv  = ce_t + 384;

    // 1: both means -> bf16
    means_kernel<<<32768, 256, 0, stream>>>(x_mid, x_deep, xm_b, xd_b);

    // 2: C = xm @ w_shallow^T  [128,2048], S=4
    gemm_mfma<<<dim3(64, 4, 1), 512, 0, stream>>>(
        xm_b, nullptr, w_shallow, nullptr, P_C, 2048, 512, 4);
    reduce_b<<<1024, 256, 0, stream>>>(P_C, sh_b, nullptr, 262144, 4, 1, 0);

    // 3: layer 1 both paths [128,2048] -> [128,1024], S=8
    gemm_mfma<<<dim3(32, 8, 2), 512, 0, stream>>>(
        xd_b, sh_b, ow1, sw1, P_D, 1024, 2048, 8);
    reduce_b<<<1024, 256, 0, stream>>>(P_D, o1_b, s1_b, 131072, 8, 2, 1);

    // 4: layer 2 both paths [128,1024] -> [128,512], S=8
    gemm_mfma<<<dim3(16, 8, 2), 512, 0, stream>>>(
        o1_b, s1_b, ow2, sw2, P_E, 512, 1024, 8);

    // 5: tail (P_E reduce + layer-3 + per-sample tail)
    tail_kernel<<<128, 256, 0, stream>>>(P_E, ow3, sw3, tw1, tw2, cw1, cw2,
                                         qw1, qw2, center, proto,
                                         ce_t, osv, csv, alv);

    // 6: finalize
    finalize_kernel<<<1, 128, 0, stream>>>(ce_t, osv, csv, alv, out);
}